// Round 16
// baseline (475.463 us; speedup 1.0000x reference)
//
#include <hip/hip_runtime.h>
#include <hip/hip_bf16.h>
#include <math.h>

// Problem constants
#define NB 8
#define NS 4096
#define NL 77
#define NLP 80     // padded L for score tiles (5 x 16)
#define NLPV 96    // padded L for PV K-dim (3 x 32)
#define ND 1280
#define NC 2048
#define NH 20
#define NDH 64
#define QK_SCALE 0.125f

typedef __attribute__((ext_vector_type(4))) float f32x4;
typedef __attribute__((ext_vector_type(8))) short bf16x8;

static __device__ __forceinline__ void gload_lds16(const void* g, void* l) {
  __builtin_amdgcn_global_load_lds(
      (const __attribute__((address_space(1))) void*)g,
      (__attribute__((address_space(3))) void*)l, 16, 0, 0);
}

#define BAR() do { asm volatile("" ::: "memory"); __builtin_amdgcn_s_barrier(); asm volatile("" ::: "memory"); } while (0)
#define LGKM0() asm volatile("s_waitcnt lgkmcnt(0)" ::: "memory")

// order-preserving float<->uint for atomicMax-based global max
static __device__ __forceinline__ unsigned enc_f(float f) {
  unsigned b = __float_as_uint(f);
  return (b & 0x80000000u) ? ~b : (b | 0x80000000u);
}
static __device__ __forceinline__ float dec_f(unsigned u) {
  return (u & 0x80000000u) ? __uint_as_float(u ^ 0x80000000u) : __uint_as_float(~u);
}

// ---------------- fused prep: cvt hs, cvt ehs, 4 weight transposes, kp/vt pad zero ----------------
__global__ __launch_bounds__(256)
void prep_kern(const float* __restrict__ hs,  __hip_bfloat16* __restrict__ hsb,
               const float* __restrict__ ehs, __hip_bfloat16* __restrict__ ehsb,
               const float* __restrict__ Wq,  __hip_bfloat16* __restrict__ wqt,
               const float* __restrict__ Wk,  const float* __restrict__ Wv,
               __hip_bfloat16* __restrict__ wkvt,
               const float* __restrict__ Wo,  __hip_bfloat16* __restrict__ wot,
               __hip_bfloat16* __restrict__ kp, __hip_bfloat16* __restrict__ vt)
{
  const int bid = blockIdx.x, t = threadIdx.x;
  if (bid < 2560) {
    const float* in; __hip_bfloat16* outp; long n; long i; long stride;
    if (bid < 2048) {
      in = hs; outp = hsb; n = (long)NB * NS * ND;
      i = ((long)bid * 256 + t) * 4; stride = 2048L * 256 * 4;
    } else {
      in = ehs; outp = ehsb; n = (long)NB * NL * NC;
      i = ((long)(bid - 2048) * 256 + t) * 4; stride = 512L * 256 * 4;
    }
    for (; i < n; i += stride) {
      float4 v = *reinterpret_cast<const float4*>(in + i);
      union { __hip_bfloat16 h[4]; ushort4 u; } r;
      r.h[0] = __float2bfloat16(v.x);
      r.h[1] = __float2bfloat16(v.y);
      r.h[2] = __float2bfloat16(v.z);
      r.h[3] = __float2bfloat16(v.w);
      *reinterpret_cast<ushort4*>(outp + i) = r.u;
    }
    return;
  }
  if (bid >= 10880) {
    // pad zeroing
    const __hip_bfloat16 z = __float2bfloat16(0.f);
    if (bid < 10888) {
      int b = bid - 10880;                 // kp rows 77..79
      for (int i = t; i < 3 * ND; i += 256)
        kp[((long)(b * NLP + NL)) * ND + i] = z;
    } else {
      int b = bid - 10888;                 // vt cols 77..95 for all (h,dh)
      for (int i = t; i < NH * NDH * (NLPV - NL); i += 256) {
        int li = i % (NLPV - NL), rowi = i / (NLPV - NL);
        vt[(((long)(b * NH)) * NDH + rowi) * NLPV + NL + li] = z;
      }
    }
    return;
  }
  // transpose roles: f32 [rows][cols] -> bf16 [cols][rows]
  __shared__ float tl[32][33];
  const float* in; __hip_bfloat16* outp; int rows, cols, idx;
  if (bid < 4160)      { idx = bid - 2560; in = Wq; outp = wqt; rows = 1280; cols = 1280; }
  else if (bid < 6720) { idx = bid - 4160; in = Wk; outp = wkvt; rows = 2048; cols = 1280; }
  else if (bid < 9280) { idx = bid - 6720; in = Wv; outp = wkvt + (size_t)ND * NC; rows = 2048; cols = 1280; }
  else                 { idx = bid - 9280; in = Wo; outp = wot; rows = 1280; cols = 1280; }
  int c0 = (idx % 40) * 32, r0 = (idx / 40) * 32;
  int tx = t & 31, ty = t >> 5;
  for (int i = ty; i < 32; i += 8) {
    int r = r0 + i, c = c0 + tx;
    tl[i][tx] = (r < rows && c < cols) ? in[(long)r * cols + c] : 0.f;
  }
  __syncthreads();
  for (int i = ty; i < 32; i += 8) {
    int oc = c0 + i, orr = r0 + tx;
    if (oc < cols && orr < rows)
      outp[(long)oc * rows + orr] = __float2bfloat16(tl[tx][i]);
  }
}

// ---------------- KV proj GEMM (m97-style) + fused repack scatter ----------------
__global__ __launch_bounds__(256)
void gemm_kv_kern(const __hip_bfloat16* __restrict__ A,
                  const __hip_bfloat16* __restrict__ Bt,
                  __hip_bfloat16* __restrict__ kp,
                  __hip_bfloat16* __restrict__ vt,
                  int M, int N, int K)
{
  __shared__ __align__(16) __hip_bfloat16 As[128 * 32];
  __shared__ __align__(16) __hip_bfloat16 Bs[128 * 32];
  const int t = threadIdx.x;
  const int lane = t & 63;
  const int w = t >> 6;
  const int wm = w >> 1, wn = w & 1;
  const int lr = lane & 15, hi = lane >> 4, lk = hi * 8;
  const long m0 = (long)blockIdx.x * 128;
  const long n0 = (long)blockIdx.y * 128;

  f32x4 acc[4][4];
#pragma unroll
  for (int mi = 0; mi < 4; ++mi)
#pragma unroll
    for (int ni = 0; ni < 4; ++ni) acc[mi][ni] = {0.f, 0.f, 0.f, 0.f};

  for (int k0 = 0; k0 < K; k0 += 32) {
    __syncthreads();
#pragma unroll
    for (int rnd = 0; rnd < 2; ++rnd) {
      int idx = rnd * 256 + t;
      int row = idx >> 2, kpp = (idx & 3) * 8;
      long arow = m0 + row; if (arow >= M) arow = M - 1;
      gload_lds16(A + arow * K + k0 + kpp, (void*)(As + idx * 8));
      long brow = n0 + row;
      gload_lds16(Bt + brow * K + k0 + kpp, (void*)(Bs + idx * 8));
    }
    __syncthreads();

    bf16x8 af[4], bfr[4];
#pragma unroll
    for (int i = 0; i < 4; ++i) {
      af[i]  = *reinterpret_cast<const bf16x8*>(As + (wm * 64 + i * 16 + lr) * 32 + lk);
      bfr[i] = *reinterpret_cast<const bf16x8*>(Bs + (wn * 64 + i * 16 + lr) * 32 + lk);
    }
#pragma unroll
    for (int mi = 0; mi < 4; ++mi)
#pragma unroll
      for (int ni = 0; ni < 4; ++ni)
        acc[mi][ni] = __builtin_amdgcn_mfma_f32_16x16x32_bf16(af[mi], bfr[ni], acc[mi][ni], 0, 0, 0);
  }

#pragma unroll
  for (int mi = 0; mi < 4; ++mi) {
#pragma unroll
    for (int r = 0; r < 4; ++r) {
      long row = m0 + wm * 64 + mi * 16 + hi * 4 + r;
      if (row < M) {
        int b = (int)(row / NL), l = (int)(row - (long)b * NL);
#pragma unroll
        for (int ni = 0; ni < 4; ++ni) {
          long col = n0 + wn * 64 + ni * 16 + lr;
          __hip_bfloat16 v = __float2bfloat16(acc[mi][ni][r]);
          if (col < ND) {
            kp[((long)(b * NLP + l)) * ND + col] = v;
          } else {
            int c2 = (int)(col - ND);
            vt[(((long)(b * NH + (c2 >> 6))) * NDH + (c2 & 63)) * NLPV + l] = v;
          }
        }
      }
    }
  }
}

// ---- Q-proj GEMM: 128x128, BK=64, dbuf 64KB LDS, 512 thr / 8 waves (64x32 out each),
//      2 blocks/CU -> 16 waves/CU; counted vmcnt; bf16 C + fused QK score-max ----
__global__ __launch_bounds__(512, 4)
void gemm_qmax_kern(const __hip_bfloat16* __restrict__ A,
                    const __hip_bfloat16* __restrict__ Bt,
                    __hip_bfloat16* __restrict__ C,
                    const __hip_bfloat16* __restrict__ kp,
                    unsigned* __restrict__ gmax,
                    int M, int N, int K)
{
  __shared__ __align__(16) __hip_bfloat16 sm[32768];   // 64 KiB
  __shared__ float wmx[8];
  char* smc = (char*)sm;

  const int t = threadIdx.x, lane = t & 63, w = t >> 6;  // 8 waves
  const int wm = w >> 2, wn = w & 3;                     // 2 x 4, per-wave 64x32 out
  const int lr = lane & 15, hi = lane >> 4;
  const int sw = lr & 7;

  int nwg = gridDim.x;
  int cpx = nwg >> 3;
  int swz = (blockIdx.x & 7) * cpx + (blockIdx.x >> 3);
  int nxt = N >> 7;
  int mt = swz / nxt, ntile = swz - mt * nxt;
  const long m0 = (long)mt * 128, n0 = (long)ntile * 128;

  const int srow  = t >> 3;                       // 0..63 (c adds 64)
  const int skoff = ((t & 7) ^ ((t >> 3) & 7)) * 8;
  const int sdst  = t * 16;                       // + c*8192 bytes

  f32x4 acc[4][2];
#pragma unroll
  for (int mi = 0; mi < 4; ++mi)
#pragma unroll
    for (int ni = 0; ni < 2; ++ni) acc[mi][ni] = {0.f, 0.f, 0.f, 0.f};

  auto stageA = [&](int b, int kt) {
#pragma unroll
    for (int c = 0; c < 2; ++c)
      gload_lds16(A + (m0 + c * 64 + srow) * (long)K + kt * 64 + skoff,
                  (void*)(smc + b * 16384 + c * 8192 + sdst));
  };
  auto stageB = [&](int b, int kt) {
#pragma unroll
    for (int c = 0; c < 2; ++c)
      gload_lds16(Bt + (n0 + c * 64 + srow) * (long)K + kt * 64 + skoff,
                  (void*)(smc + 32768 + b * 16384 + c * 8192 + sdst));
  };

  const int NT = K >> 6;
  stageA(0, 0); stageB(0, 0);
  stageA(1, 1); stageB(1, 1);
  asm volatile("s_waitcnt vmcnt(4)" ::: "memory");   // tile 0 resident; tile 1 in flight
  BAR();

  for (int t2 = 0; t2 < NT; ++t2) {
    const int b = t2 & 1;
    const char* pa = smc + b * 16384;
    const char* pb = smc + 32768 + b * 16384;
    const bool pf = (t2 + 2 < NT);

    bf16x8 af[4][2], bfr[2][2];
#pragma unroll
    for (int mi = 0; mi < 4; ++mi) {
      int row = wm * 64 + mi * 16 + lr;
#pragma unroll
      for (int kk = 0; kk < 2; ++kk)
        af[mi][kk] = *reinterpret_cast<const bf16x8*>(
            pa + row * 128 + ((((kk * 4 + hi) ^ sw)) << 4));
    }
#pragma unroll
    for (int ni = 0; ni < 2; ++ni) {
      int row = wn * 32 + ni * 16 + lr;
#pragma unroll
      for (int kk = 0; kk < 2; ++kk)
        bfr[ni][kk] = *reinterpret_cast<const bf16x8*>(
            pb + row * 128 + ((((kk * 4 + hi) ^ sw)) << 4));
    }
    __builtin_amdgcn_s_setprio(1);
#pragma unroll
    for (int mi = 0; mi < 4; ++mi)
#pragma unroll
      for (int ni = 0; ni < 2; ++ni) {
        acc[mi][ni] = __builtin_amdgcn_mfma_f32_16x16x32_bf16(af[mi][0], bfr[ni][0], acc[mi][ni], 0, 0, 0);
        acc[mi][ni] = __builtin_amdgcn_mfma_f32_16x16x32_bf16(af[mi][1], bfr[ni][1], acc[mi][ni], 0, 0, 0);
      }
    __builtin_amdgcn_s_setprio(0);

    LGKM0();
    BAR();
    if (pf) { stageA(b, t2 + 2); stageB(b, t2 + 2); }
    if (pf) { asm volatile("s_waitcnt vmcnt(4)" ::: "memory"); }   // tile t2+1 resident
    else    { asm volatile("s_waitcnt vmcnt(0)" ::: "memory"); }
    BAR();
  }

  // epilogue: bf16 store + LDS staging for fused QK max
  __hip_bfloat16* qsl = (__hip_bfloat16*)smc;   // [128][128], 16B-block XOR swizzle
#pragma unroll
  for (int mi = 0; mi < 4; ++mi)
#pragma unroll
    for (int r = 0; r < 4; ++r) {
      int rowl = wm * 64 + mi * 16 + hi * 4 + r;
      long row = m0 + rowl;
#pragma unroll
      for (int ni = 0; ni < 2; ++ni) {
        int col = wn * 32 + ni * 16 + lr;
        __hip_bfloat16 v = __float2bfloat16(acc[mi][ni][r]);
        C[row * N + n0 + col] = v;
        int bw = (col >> 3) ^ (rowl & 7);
        qsl[rowl * 128 + (bw << 3) + (col & 7)] = v;
      }
    }
  LGKM0();
  BAR();
  const int bb = (int)(m0 >> 12);             // batch index (NS=4096 rows per batch)
  float mx = -1e30f;
  {
    const int hh = w >> 2;                    // wave's head half (2 heads per 128-col tile)
    const int h = (int)(n0 >> 6) + hh;
    bf16x8 bk0[5], bk1[5];
#pragma unroll
    for (int lt = 0; lt < 5; ++lt) {
      const __hip_bfloat16* Kr = kp + ((long)(bb * NLP + lt * 16 + lr)) * ND + h * NDH + hi * 8;
      bk0[lt] = *reinterpret_cast<const bf16x8*>(Kr);
      bk1[lt] = *reinterpret_cast<const bf16x8*>(Kr + 32);
    }
#pragma unroll
    for (int su = 0; su < 2; ++su) {
      int qrow = (w & 3) * 32 + su * 16 + lr;  // qrow&7 == lr&7
      int bi0 = (hh * 8 + hi)     ^ sw;
      int bi1 = (hh * 8 + 4 + hi) ^ sw;
      bf16x8 aq0 = *reinterpret_cast<const bf16x8*>(qsl + qrow * 128 + (bi0 << 3));
      bf16x8 aq1 = *reinterpret_cast<const bf16x8*>(qsl + qrow * 128 + (bi1 << 3));
#pragma unroll
      for (int lt = 0; lt < 5; ++lt) {
        f32x4 sc = {0.f, 0.f, 0.f, 0.f};
        sc = __builtin_amdgcn_mfma_f32_16x16x32_bf16(aq0, bk0[lt], sc, 0, 0, 0);
        sc = __builtin_amdgcn_mfma_f32_16x16x32_bf16(aq1, bk1[lt], sc, 0, 0, 0);
        if ((lt < 4) || (lr < 13)) {          // col l = lt*16 + lr < 77
#pragma unroll
          for (int r = 0; r < 4; ++r) mx = fmaxf(mx, sc[r]);
        }
      }
    }
  }
#pragma unroll
  for (int k = 32; k >= 1; k >>= 1) mx = fmaxf(mx, __shfl_xor(mx, k));
  if (lane == 0) wmx[w] = mx;
  LGKM0();
  BAR();
  if (t == 0) {
    float mm = wmx[0];
#pragma unroll
    for (int i = 1; i < 8; ++i) mm = fmaxf(mm, wmx[i]);
    atomicMax(gmax, enc_f(mm * QK_SCALE));
  }
}

// ---- O-proj GEMM: 128x128, BK=64, dbuf 64KB LDS, 512 thr / 8 waves; f32 C + bias ----
__global__ __launch_bounds__(512, 4)
void gemm_out_kern(const __hip_bfloat16* __restrict__ A,
                   const __hip_bfloat16* __restrict__ Bt,
                   float* __restrict__ C, const float* __restrict__ bias,
                   int M, int N, int K)
{
  __shared__ __align__(16) __hip_bfloat16 sm[32768];   // 64 KiB
  char* smc = (char*)sm;

  const int t = threadIdx.x, lane = t & 63, w = t >> 6;
  const int wm = w >> 2, wn = w & 3;
  const int lr = lane & 15, hi = lane >> 4;
  const int sw = lr & 7;

  int nwg = gridDim.x;
  int cpx = nwg >> 3;
  int swz = (blockIdx.x & 7) * cpx + (blockIdx.x >> 3);
  int nxt = N >> 7;
  int mt = swz / nxt, ntile = swz - mt * nxt;
  const long m0 = (long)mt * 128, n0 = (long)ntile * 128;

  const int srow  = t >> 3;
  const int skoff = ((t & 7) ^ ((t >> 3) & 7)) * 8;
  const int sdst  = t * 16;

  f32x4 acc[4][2];
#pragma unroll
  for (int mi = 0; mi < 4; ++mi)
#pragma unroll
    for (int ni = 0; ni < 2; ++ni) acc[mi][ni] = {0.f, 0.f, 0.f, 0.f};

  auto stageA = [&](int b, int kt) {
#pragma unroll
    for (int c = 0; c < 2; ++c)
      gload_lds16(A + (m0 + c * 64 + srow) * (long)K + kt * 64 + skoff,
                  (void*)(smc + b * 16384 + c * 8192 + sdst));
  };
  auto stageB = [&](int b, int kt) {
#pragma unroll
    for (int c = 0; c < 2; ++c)
      gload_lds16(Bt + (n0 + c * 64 + srow) * (long)K + kt * 64 + skoff,
                  (void*)(smc + 32768 + b * 16384 + c * 8192 + sdst));
  };

  const int NT = K >> 6;
  stageA(0, 0); stageB(0, 0);
  stageA(1, 1); stageB(1, 1);
  asm volatile("s_waitcnt vmcnt(4)" ::: "memory");
  BAR();

  for (int t2 = 0; t2 < NT; ++t2) {
    const int b = t2 & 1;
    const char* pa = smc + b * 16384;
    const char* pb = smc + 32768 + b * 16384;
    const bool pf = (t2 + 2 < NT);

    bf16x8 af[4][2], bfr[2][2];
#pragma unroll
    for (int mi = 0; mi < 4; ++mi) {
      int row = wm * 64 + mi * 16 + lr;
#pragma unroll
      for (int kk = 0; kk < 2; ++kk)
        af[mi][kk] = *reinterpret_cast<const bf16x8*>(
            pa + row * 128 + ((((kk * 4 + hi) ^ sw)) << 4));
    }
#pragma unroll
    for (int ni = 0; ni < 2; ++ni) {
      int row = wn * 32 + ni * 16 + lr;
#pragma unroll
      for (int kk = 0; kk < 2; ++kk)
        bfr[ni][kk] = *reinterpret_cast<const bf16x8*>(
            pb + row * 128 + ((((kk * 4 + hi) ^ sw)) << 4));
    }
    __builtin_amdgcn_s_setprio(1);
#pragma unroll
    for (int mi = 0; mi < 4; ++mi)
#pragma unroll
      for (int ni = 0; ni < 2; ++ni) {
        acc[mi][ni] = __builtin_amdgcn_mfma_f32_16x16x32_bf16(af[mi][0], bfr[ni][0], acc[mi][ni], 0, 0, 0);
        acc[mi][ni] = __builtin_amdgcn_mfma_f32_16x16x32_bf16(af[mi][1], bfr[ni][1], acc[mi][ni], 0, 0, 0);
      }
    __builtin_amdgcn_s_setprio(0);

    LGKM0();
    BAR();
    if (pf) { stageA(b, t2 + 2); stageB(b, t2 + 2); }
    if (pf) { asm volatile("s_waitcnt vmcnt(4)" ::: "memory"); }
    else    { asm volatile("s_waitcnt vmcnt(0)" ::: "memory"); }
    BAR();
  }

  float bv[2];
#pragma unroll
  for (int ni = 0; ni < 2; ++ni) bv[ni] = bias[n0 + wn * 32 + ni * 16 + lr];
#pragma unroll
  for (int mi = 0; mi < 4; ++mi)
#pragma unroll
    for (int r = 0; r < 4; ++r) {
      long row = m0 + wm * 64 + mi * 16 + hi * 4 + r;
#pragma unroll
      for (int ni = 0; ni < 2; ++ni) {
        long col = n0 + wn * 32 + ni * 16 + lr;
        C[row * N + col] = acc[mi][ni][r] + bv[ni];
      }
    }
}

// ---------------- pass B: scores + bias + softmax + PV ----------------
// Block = 64 s-rows x 10 heads (blockIdx.z selects head half); rs staged once per block.
__global__ __launch_bounds__(256)
void attn_kern(const __hip_bfloat16* __restrict__ qb,
               const __hip_bfloat16* __restrict__ kp,
               const __hip_bfloat16* __restrict__ vt,
               const float* __restrict__ rs,
               const unsigned* __restrict__ gmax,
               const float* __restrict__ sigma,
               __hip_bfloat16* __restrict__ ao_out)
{
  __shared__ __align__(16) float rsl[64][80];
  __shared__ __align__(16) __hip_bfloat16 pl[4][16][NLPV];
  int t = threadIdx.x, lane = t & 63, wi = t >> 6;
  int b = blockIdx.y;
  int s0 = blockIdx.x * 64;
  int h0 = blockIdx.z * (NH / 2);
  int lr = lane & 15, hi = lane >> 4, lk = hi * 8;
  const float c = log1pf(sigma[0] * 0.1f) * dec_f(gmax[0]);

  for (int i = t; i < 64 * NL; i += 256) {
    int rr = i / NL, cc = i - rr * NL;
    rsl[rr][cc] = rs[((long)(b * NS + s0 + rr)) * NL + cc] * c;
  }
#pragma unroll
  for (int r = 0; r < 4; ++r)
    pl[wi][hi * 4 + r][80 + lr] = __float2bfloat16(0.f);
  __syncthreads();

  const int rw = wi * 16;
  const __hip_bfloat16* Qrow = qb + ((long)(b * NS + s0 + rw + lr)) * ND;
  const __hip_bfloat16* Krow = kp + ((long)(b * NLP + lr)) * ND;

  for (int h = h0; h < h0 + NH / 2; ++h) {
    const __hip_bfloat16* Qp = Qrow + h * NDH + lk;
    bf16x8 aq0 = *reinterpret_cast<const bf16x8*>(Qp);
    bf16x8 aq1 = *reinterpret_cast<const bf16x8*>(Qp + 32);

    f32x4 sc[5];
#pragma unroll
    for (int lt = 0; lt < 5; ++lt) {
      const __hip_bfloat16* Kr = Krow + (long)lt * 16 * ND + h * NDH + lk;
      bf16x8 bk0 = *reinterpret_cast<const bf16x8*>(Kr);
      bf16x8 bk1 = *reinterpret_cast<const bf16x8*>(Kr + 32);
      f32x4 z = {0.f, 0.f, 0.f, 0.f};
      z = __builtin_amdgcn_mfma_f32_16x16x32_bf16(aq0, bk0, z, 0, 0, 0);
      sc[lt] = __builtin_amdgcn_mfma_f32_16x16x32_bf16(aq1, bk1, z, 0, 0, 0);
    }

    float sv[5][4];
    float pm[4] = {-1e30f, -1e30f, -1e30f, -1e30f};
#pragma unroll
    for (int lt = 0; lt < 5; ++lt) {
      int l = lt * 16 + lr;
#pragma unroll
      for (int r = 0; r < 4; ++r) {
        if (l < NL) {
          float v = sc[lt][r] * QK_SCALE + rsl[rw + hi * 4 + r][l];
          sv[lt][r] = v;
          pm[r] = fmaxf(pm[r], v);
        } else {
          sv[lt][r] = -1e30f;
        }
      }
    }
#pragma unroll
    for (int r = 0; r < 4; ++r)
#pragma unroll
      for (int k = 8; k >= 1; k >>= 1) pm[r] = fmaxf(pm[r], __shfl_xor(pm[r], k));

    float p[5][4];
    float psum[4] = {0.f, 0.f, 0.f, 0.f};
#pragma unroll
    for (int lt = 0; lt < 5; ++lt) {
      int l = lt * 16 + lr;
#pragma unroll
      for (int r = 0; r < 4; ++r) {
        float e = (l < NL) ? __expf(sv[lt][r] - pm[r]) : 0.f;
        p[lt][r] = e;
        psum[r] += e;
      }
    }
#pragma unroll
    for (int r = 0; r < 4; ++r)
#pragma unroll
      for (int k = 8; k >= 1; k >>= 1) psum[r] += __shfl_xor(psum[r], k);
    float rinv[4];
#pragma unroll
    for (int r = 0; r < 4; ++r) rinv[r] = 1.f / psum[r];

    // fence (1): prior head's PV reads retired (WAR + TBAA-safe)
    LGKM0();

#pragma unroll
    for (int lt = 0; lt < 5; ++lt)
#pragma unroll
      for (int r = 0; r < 4; ++r)
        pl[wi][hi * 4 + r][lt * 16 + lr] = __float2bfloat16(p[lt][r]);

    // fence (2): P-writes complete before PV reads issue (RAW-safe)
    LGKM0();

    f32x4 ao[4];
#pragma unroll
    for (int nt = 0; nt < 4; ++nt) ao[nt] = {0.f, 0.f, 0.f, 0.f};
    const __hip_bfloat16* Vb = vt + ((long)((b * NH + h) * NDH)) * NLPV;
#pragma unroll
    for (int ks = 0; ks < 3; ++ks) {
      bf16x8 pa = *reinterpret_cast<const bf16x8*>(&pl[wi][lr][ks * 32 + lk]);
#pragma unroll
      for (int nt = 0; nt < 4; ++nt) {
        bf16x8 bv = *reinterpret_cast<const bf16x8*>(Vb + ((long)(nt * 16 + lr)) * NLPV + ks * 32 + lk);
        ao[nt] = __builtin_amdgcn_mfma_f32_16x16x32_bf16(pa, bv, ao[nt], 0, 0, 0);
      }
    }

#pragma unroll
    for (int nt = 0; nt < 4; ++nt)
#pragma unroll
      for (int r = 0; r < 4; ++r) {
        int srow = s0 + rw + hi * 4 + r;
        ao_out[((long)(b * NS + srow)) * ND + h * NDH + nt * 16 + lr] =
            __float2bfloat16(ao[nt][r] * rinv[r]);
      }
  }
}

// ---------------- launcher ----------------
extern "C" void kernel_launch(void* const* d_in, const int* in_sizes, int n_in,
                              void* d_out, int out_size, void* d_ws, size_t ws_size,
                              hipStream_t stream)
{
  const float* hs    = (const float*)d_in[0];
  const float* ehs   = (const float*)d_in[1];
  const float* rs    = (const float*)d_in[2];
  const float* Wq    = (const float*)d_in[3];
  const float* Wk    = (const float*)d_in[4];
  const float* Wv    = (const float*)d_in[5];
  const float* Wo    = (const float*)d_in[6];
  const float* bo    = (const float*)d_in[7];
  const float* sigma = (const float*)d_in[8];
  float* out = (float*)d_out;

  char* ws = (char*)d_ws;
  size_t off = 0;
  auto alloc = [&](size_t bytes) {
    void* p = ws + off;
    off = (off + bytes + 255) & ~(size_t)255;
    return p;
  };
  __hip_bfloat16* hsb  = (__hip_bfloat16*)alloc((size_t)NB * NS * ND * 2);   // hs bf16; reused as attn_out
  __hip_bfloat16* qb   = (__hip_bfloat16*)alloc((size_t)NB * NS * ND * 2);
  __hip_bfloat16* wqt  = (__hip_bfloat16*)alloc((size_t)ND * ND * 2);
  __hip_bfloat16* wkvt = (__hip_bfloat16*)alloc((size_t)2560 * NC * 2);      // [Wk^T ; Wv^T]
  __hip_bfloat16* wot  = (__hip_bfloat16*)alloc((size_t)ND * ND * 2);
  __hip_bfloat16* ehsb = (__hip_bfloat16*)alloc((size_t)NB * NL * NC * 2);
  __hip_bfloat16* kp   = (__hip_bfloat16*)alloc((size_t)NB * NLP * ND * 2);
  __hip_bfloat16* vt   = (__hip_bfloat16*)alloc((size_t)NB * NH * NDH * NLPV * 2);
  unsigned* gmax = (unsigned*)alloc(256);

  // 0) init global score-max (encoded; 0 == -inf key). Must run each call.
  hipMemsetAsync(gmax, 0, 4, stream);

  // 1) fused prep: cvt hs, cvt ehs, 4 weight transposes, kp/vt pad zeroing
  prep_kern<<<10896, 256, 0, stream>>>(hs, hsb, ehs, ehsb, Wq, wqt, Wk, Wv, wkvt, Wo, wot, kp, vt);

  // 2) KV = ehs @ [Wk|Wv] with fused repack scatter to kp/vt
  gemm_kv_kern<<<dim3(5, 20), 256, 0, stream>>>(ehsb, wkvt, kp, vt, NB * NL, 2560, NC);

  // 3) Q = hs @ Wq (bf16 out) + fused global score-max (atomic); 512-thr / 16 waves/CU
  gemm_qmax_kern<<<2560, 512, 0, stream>>>(hsb, wqt, qb, kp, gmax, NB * NS, ND, ND);

  // 4) attention (10 heads per block via z-split -> 4 blocks/CU) -> attn_out (reuses hsb)
  attn_kern<<<dim3(NS / 64, NB, 2), 256, 0, stream>>>(qb, kp, vt, rs, gmax, sigma, hsb);

  // 5) out = attn_out @ Wo + bo  (f32 out); 512-thr / 16 waves/CU
  gemm_out_kern<<<2560, 512, 0, stream>>>(hsb, wot, out, bo, NB * NS, ND, ND);
}

// Round 17
// 467.585 us; speedup vs baseline: 1.0168x; 1.0168x over previous
//
#include <hip/hip_runtime.h>
#include <hip/hip_bf16.h>
#include <math.h>

// Problem constants
#define NB 8
#define NS 4096
#define NL 77
#define NLP 80     // padded L for score tiles (5 x 16)
#define NLPV 96    // padded L for PV K-dim (3 x 32)
#define ND 1280
#define NC 2048
#define NH 20
#define NDH 64
#define QK_SCALE 0.125f

typedef __attribute__((ext_vector_type(4))) float f32x4;
typedef __attribute__((ext_vector_type(8))) short bf16x8;

static __device__ __forceinline__ void gload_lds16(const void* g, void* l) {
  __builtin_amdgcn_global_load_lds(
      (const __attribute__((address_space(1))) void*)g,
      (__attribute__((address_space(3))) void*)l, 16, 0, 0);
}

#define BAR() do { asm volatile("" ::: "memory"); __builtin_amdgcn_s_barrier(); asm volatile("" ::: "memory"); } while (0)
#define LGKM0() asm volatile("s_waitcnt lgkmcnt(0)" ::: "memory")

// order-preserving float<->uint for atomicMax-based global max
static __device__ __forceinline__ unsigned enc_f(float f) {
  unsigned b = __float_as_uint(f);
  return (b & 0x80000000u) ? ~b : (b | 0x80000000u);
}
static __device__ __forceinline__ float dec_f(unsigned u) {
  return (u & 0x80000000u) ? __uint_as_float(u ^ 0x80000000u) : __uint_as_float(~u);
}

// ---------------- fused prep: cvt hs, cvt ehs, 4 weight transposes, kp/vt pad zero ----------------
__global__ __launch_bounds__(256)
void prep_kern(const float* __restrict__ hs,  __hip_bfloat16* __restrict__ hsb,
               const float* __restrict__ ehs, __hip_bfloat16* __restrict__ ehsb,
               const float* __restrict__ Wq,  __hip_bfloat16* __restrict__ wqt,
               const float* __restrict__ Wk,  const float* __restrict__ Wv,
               __hip_bfloat16* __restrict__ wkvt,
               const float* __restrict__ Wo,  __hip_bfloat16* __restrict__ wot,
               __hip_bfloat16* __restrict__ kp, __hip_bfloat16* __restrict__ vt)
{
  const int bid = blockIdx.x, t = threadIdx.x;
  if (bid < 2560) {
    const float* in; __hip_bfloat16* outp; long n; long i; long stride;
    if (bid < 2048) {
      in = hs; outp = hsb; n = (long)NB * NS * ND;
      i = ((long)bid * 256 + t) * 4; stride = 2048L * 256 * 4;
    } else {
      in = ehs; outp = ehsb; n = (long)NB * NL * NC;
      i = ((long)(bid - 2048) * 256 + t) * 4; stride = 512L * 256 * 4;
    }
    for (; i < n; i += stride) {
      float4 v = *reinterpret_cast<const float4*>(in + i);
      union { __hip_bfloat16 h[4]; ushort4 u; } r;
      r.h[0] = __float2bfloat16(v.x);
      r.h[1] = __float2bfloat16(v.y);
      r.h[2] = __float2bfloat16(v.z);
      r.h[3] = __float2bfloat16(v.w);
      *reinterpret_cast<ushort4*>(outp + i) = r.u;
    }
    return;
  }
  if (bid >= 10880) {
    // pad zeroing
    const __hip_bfloat16 z = __float2bfloat16(0.f);
    if (bid < 10888) {
      int b = bid - 10880;                 // kp rows 77..79
      for (int i = t; i < 3 * ND; i += 256)
        kp[((long)(b * NLP + NL)) * ND + i] = z;
    } else {
      int b = bid - 10888;                 // vt cols 77..95 for all (h,dh)
      for (int i = t; i < NH * NDH * (NLPV - NL); i += 256) {
        int li = i % (NLPV - NL), rowi = i / (NLPV - NL);
        vt[(((long)(b * NH)) * NDH + rowi) * NLPV + NL + li] = z;
      }
    }
    return;
  }
  // transpose roles: f32 [rows][cols] -> bf16 [cols][rows]
  __shared__ float tl[32][33];
  const float* in; __hip_bfloat16* outp; int rows, cols, idx;
  if (bid < 4160)      { idx = bid - 2560; in = Wq; outp = wqt; rows = 1280; cols = 1280; }
  else if (bid < 6720) { idx = bid - 4160; in = Wk; outp = wkvt; rows = 2048; cols = 1280; }
  else if (bid < 9280) { idx = bid - 6720; in = Wv; outp = wkvt + (size_t)ND * NC; rows = 2048; cols = 1280; }
  else                 { idx = bid - 9280; in = Wo; outp = wot; rows = 1280; cols = 1280; }
  int c0 = (idx % 40) * 32, r0 = (idx / 40) * 32;
  int tx = t & 31, ty = t >> 5;
  for (int i = ty; i < 32; i += 8) {
    int r = r0 + i, c = c0 + tx;
    tl[i][tx] = (r < rows && c < cols) ? in[(long)r * cols + c] : 0.f;
  }
  __syncthreads();
  for (int i = ty; i < 32; i += 8) {
    int oc = c0 + i, orr = r0 + tx;
    if (oc < cols && orr < rows)
      outp[(long)oc * rows + orr] = __float2bfloat16(tl[tx][i]);
  }
}

// ---------------- KV proj GEMM (m97-style) + fused repack scatter ----------------
__global__ __launch_bounds__(256)
void gemm_kv_kern(const __hip_bfloat16* __restrict__ A,
                  const __hip_bfloat16* __restrict__ Bt,
                  __hip_bfloat16* __restrict__ kp,
                  __hip_bfloat16* __restrict__ vt,
                  int M, int N, int K)
{
  __shared__ __align__(16) __hip_bfloat16 As[128 * 32];
  __shared__ __align__(16) __hip_bfloat16 Bs[128 * 32];
  const int t = threadIdx.x;
  const int lane = t & 63;
  const int w = t >> 6;
  const int wm = w >> 1, wn = w & 1;
  const int lr = lane & 15, hi = lane >> 4, lk = hi * 8;
  const long m0 = (long)blockIdx.x * 128;
  const long n0 = (long)blockIdx.y * 128;

  f32x4 acc[4][4];
#pragma unroll
  for (int mi = 0; mi < 4; ++mi)
#pragma unroll
    for (int ni = 0; ni < 4; ++ni) acc[mi][ni] = {0.f, 0.f, 0.f, 0.f};

  for (int k0 = 0; k0 < K; k0 += 32) {
    __syncthreads();
#pragma unroll
    for (int rnd = 0; rnd < 2; ++rnd) {
      int idx = rnd * 256 + t;
      int row = idx >> 2, kpp = (idx & 3) * 8;
      long arow = m0 + row; if (arow >= M) arow = M - 1;
      gload_lds16(A + arow * K + k0 + kpp, (void*)(As + idx * 8));
      long brow = n0 + row;
      gload_lds16(Bt + brow * K + k0 + kpp, (void*)(Bs + idx * 8));
    }
    __syncthreads();

    bf16x8 af[4], bfr[4];
#pragma unroll
    for (int i = 0; i < 4; ++i) {
      af[i]  = *reinterpret_cast<const bf16x8*>(As + (wm * 64 + i * 16 + lr) * 32 + lk);
      bfr[i] = *reinterpret_cast<const bf16x8*>(Bs + (wn * 64 + i * 16 + lr) * 32 + lk);
    }
#pragma unroll
    for (int mi = 0; mi < 4; ++mi)
#pragma unroll
      for (int ni = 0; ni < 4; ++ni)
        acc[mi][ni] = __builtin_amdgcn_mfma_f32_16x16x32_bf16(af[mi], bfr[ni], acc[mi][ni], 0, 0, 0);
  }

#pragma unroll
  for (int mi = 0; mi < 4; ++mi) {
#pragma unroll
    for (int r = 0; r < 4; ++r) {
      long row = m0 + wm * 64 + mi * 16 + hi * 4 + r;
      if (row < M) {
        int b = (int)(row / NL), l = (int)(row - (long)b * NL);
#pragma unroll
        for (int ni = 0; ni < 4; ++ni) {
          long col = n0 + wn * 64 + ni * 16 + lr;
          __hip_bfloat16 v = __float2bfloat16(acc[mi][ni][r]);
          if (col < ND) {
            kp[((long)(b * NLP + l)) * ND + col] = v;
          } else {
            int c2 = (int)(col - ND);
            vt[(((long)(b * NH + (c2 >> 6))) * NDH + (c2 & 63)) * NLPV + l] = v;
          }
        }
      }
    }
  }
}

// ---- Q-proj GEMM: 128x128, BK=64, dbuf 64KB LDS, counted vmcnt; bf16 C + fused QK score-max ----
__global__ __launch_bounds__(256, 2)
void gemm_qmax_kern(const __hip_bfloat16* __restrict__ A,
                    const __hip_bfloat16* __restrict__ Bt,
                    __hip_bfloat16* __restrict__ C,
                    const __hip_bfloat16* __restrict__ kp,
                    unsigned* __restrict__ gmax,
                    int M, int N, int K)
{
  __shared__ __align__(16) __hip_bfloat16 sm[32768];   // 64 KiB
  char* smc = (char*)sm;

  const int t = threadIdx.x, lane = t & 63, w = t >> 6;
  const int wm = w >> 1, wn = w & 1;
  const int lr = lane & 15, hi = lane >> 4;
  const int sw = lr & 7;

  int nwg = gridDim.x;
  int cpx = nwg >> 3;
  int swz = (blockIdx.x & 7) * cpx + (blockIdx.x >> 3);
  int nxt = N >> 7;
  int mt = swz / nxt, ntile = swz - mt * nxt;
  const long m0 = (long)mt * 128, n0 = (long)ntile * 128;

  const int srow  = t >> 3;
  const int skoff = ((t & 7) ^ (srow & 7)) * 8;
  const int sdst  = t * 16;

  f32x4 acc[4][4];
#pragma unroll
  for (int mi = 0; mi < 4; ++mi)
#pragma unroll
    for (int ni = 0; ni < 4; ++ni) acc[mi][ni] = {0.f, 0.f, 0.f, 0.f};

  auto stageA = [&](int b, int kt) {
#pragma unroll
    for (int c = 0; c < 4; ++c)
      gload_lds16(A + (m0 + c * 32 + srow) * (long)K + kt * 64 + skoff,
                  (void*)(smc + b * 16384 + c * 4096 + sdst));
  };
  auto stageB = [&](int b, int kt) {
#pragma unroll
    for (int c = 0; c < 4; ++c)
      gload_lds16(Bt + (n0 + c * 32 + srow) * (long)K + kt * 64 + skoff,
                  (void*)(smc + 32768 + b * 16384 + c * 4096 + sdst));
  };

  const int NT = K >> 6;
  stageA(0, 0); stageB(0, 0);
  stageA(1, 1); stageB(1, 1);
  asm volatile("s_waitcnt vmcnt(8)" ::: "memory");
  BAR();

  for (int t2 = 0; t2 < NT; ++t2) {
    const int b = t2 & 1;
    const char* pa = smc + b * 16384;
    const char* pb = smc + 32768 + b * 16384;
    const bool pf = (t2 + 2 < NT);

    bf16x8 af[4][2], bfr[4][2];
#pragma unroll
    for (int mi = 0; mi < 4; ++mi) {
      int row = wm * 64 + mi * 16 + lr;
#pragma unroll
      for (int kk = 0; kk < 2; ++kk)
        af[mi][kk] = *reinterpret_cast<const bf16x8*>(
            pa + row * 128 + ((((kk * 4 + hi) ^ sw)) << 4));
    }
#pragma unroll
    for (int ni = 0; ni < 4; ++ni) {
      int row = wn * 64 + ni * 16 + lr;
#pragma unroll
      for (int kk = 0; kk < 2; ++kk)
        bfr[ni][kk] = *reinterpret_cast<const bf16x8*>(
            pb + row * 128 + ((((kk * 4 + hi) ^ sw)) << 4));
    }
    __builtin_amdgcn_s_setprio(1);
#pragma unroll
    for (int mi = 0; mi < 4; ++mi)
#pragma unroll
      for (int ni = 0; ni < 4; ++ni) {
        acc[mi][ni] = __builtin_amdgcn_mfma_f32_16x16x32_bf16(af[mi][0], bfr[ni][0], acc[mi][ni], 0, 0, 0);
        acc[mi][ni] = __builtin_amdgcn_mfma_f32_16x16x32_bf16(af[mi][1], bfr[ni][1], acc[mi][ni], 0, 0, 0);
      }
    __builtin_amdgcn_s_setprio(0);

    LGKM0();
    BAR();
    if (pf) { stageA(b, t2 + 2); stageB(b, t2 + 2); }
    if (pf) { asm volatile("s_waitcnt vmcnt(8)" ::: "memory"); }
    else    { asm volatile("s_waitcnt vmcnt(0)" ::: "memory"); }
    BAR();
  }

  // epilogue: bf16 store + LDS staging for fused QK max
  __hip_bfloat16* qsl = (__hip_bfloat16*)smc;   // [128][128], 16B-block XOR swizzle
#pragma unroll
  for (int mi = 0; mi < 4; ++mi)
#pragma unroll
    for (int r = 0; r < 4; ++r) {
      int rowl = wm * 64 + mi * 16 + hi * 4 + r;
      long row = m0 + rowl;
#pragma unroll
      for (int ni = 0; ni < 4; ++ni) {
        int col = wn * 64 + ni * 16 + lr;
        __hip_bfloat16 v = __float2bfloat16(acc[mi][ni][r]);
        C[row * N + n0 + col] = v;
        int bw = (col >> 3) ^ (rowl & 7);
        qsl[rowl * 128 + (bw << 3) + (col & 7)] = v;
      }
    }
  LGKM0();
  BAR();
  const int bb = (int)(m0 >> 12);             // batch index (NS=4096 rows per batch)
  float mx = -1e30f;
#pragma unroll
  for (int hh = 0; hh < 2; ++hh) {
    const int h = (int)(n0 >> 6) + hh;        // two complete heads per 128-col tile
    bf16x8 bk0[5], bk1[5];
#pragma unroll
    for (int lt = 0; lt < 5; ++lt) {
      const __hip_bfloat16* Kr = kp + ((long)(bb * NLP + lt * 16 + lr)) * ND + h * NDH + hi * 8;
      bk0[lt] = *reinterpret_cast<const bf16x8*>(Kr);
      bk1[lt] = *reinterpret_cast<const bf16x8*>(Kr + 32);
    }
#pragma unroll
    for (int su = 0; su < 2; ++su) {
      int qrow = (w * 2 + su) * 16 + lr;      // qrow&7 == lr&7
      int bi0 = (hh * 8 + hi)     ^ sw;
      int bi1 = (hh * 8 + 4 + hi) ^ sw;
      bf16x8 aq0 = *reinterpret_cast<const bf16x8*>(qsl + qrow * 128 + (bi0 << 3));
      bf16x8 aq1 = *reinterpret_cast<const bf16x8*>(qsl + qrow * 128 + (bi1 << 3));
#pragma unroll
      for (int lt = 0; lt < 5; ++lt) {
        f32x4 sc = {0.f, 0.f, 0.f, 0.f};
        sc = __builtin_amdgcn_mfma_f32_16x16x32_bf16(aq0, bk0[lt], sc, 0, 0, 0);
        sc = __builtin_amdgcn_mfma_f32_16x16x32_bf16(aq1, bk1[lt], sc, 0, 0, 0);
        if ((lt < 4) || (lr < 13)) {          // col l = lt*16 + lr < 77
#pragma unroll
          for (int r = 0; r < 4; ++r) mx = fmaxf(mx, sc[r]);
        }
      }
    }
  }
#pragma unroll
  for (int k = 32; k >= 1; k >>= 1) mx = fmaxf(mx, __shfl_xor(mx, k));
  float* wmx = (float*)(smc + 32768);
  if (lane == 0) wmx[w] = mx;
  LGKM0();
  BAR();
  if (t == 0) {
    float mm = fmaxf(fmaxf(wmx[0], wmx[1]), fmaxf(wmx[2], wmx[3]));
    atomicMax(gmax, enc_f(mm * QK_SCALE));
  }
}

// ---- O-proj GEMM: 128x128, BK=64, dbuf 64KB LDS, counted vmcnt; f32 C + bias ----
__global__ __launch_bounds__(256, 2)
void gemm_out_kern(const __hip_bfloat16* __restrict__ A,
                   const __hip_bfloat16* __restrict__ Bt,
                   float* __restrict__ C, const float* __restrict__ bias,
                   int M, int N, int K)
{
  __shared__ __align__(16) __hip_bfloat16 sm[32768];   // 64 KiB
  char* smc = (char*)sm;

  const int t = threadIdx.x, lane = t & 63, w = t >> 6;
  const int wm = w >> 1, wn = w & 1;
  const int lr = lane & 15, hi = lane >> 4;
  const int sw = lr & 7;

  int nwg = gridDim.x;
  int cpx = nwg >> 3;
  int swz = (blockIdx.x & 7) * cpx + (blockIdx.x >> 3);
  int nxt = N >> 7;
  int mt = swz / nxt, ntile = swz - mt * nxt;
  const long m0 = (long)mt * 128, n0 = (long)ntile * 128;

  const int srow  = t >> 3;
  const int skoff = ((t & 7) ^ (srow & 7)) * 8;
  const int sdst  = t * 16;

  f32x4 acc[4][4];
#pragma unroll
  for (int mi = 0; mi < 4; ++mi)
#pragma unroll
    for (int ni = 0; ni < 4; ++ni) acc[mi][ni] = {0.f, 0.f, 0.f, 0.f};

  auto stageA = [&](int b, int kt) {
#pragma unroll
    for (int c = 0; c < 4; ++c)
      gload_lds16(A + (m0 + c * 32 + srow) * (long)K + kt * 64 + skoff,
                  (void*)(smc + b * 16384 + c * 4096 + sdst));
  };
  auto stageB = [&](int b, int kt) {
#pragma unroll
    for (int c = 0; c < 4; ++c)
      gload_lds16(Bt + (n0 + c * 32 + srow) * (long)K + kt * 64 + skoff,
                  (void*)(smc + 32768 + b * 16384 + c * 4096 + sdst));
  };

  const int NT = K >> 6;
  stageA(0, 0); stageB(0, 0);
  stageA(1, 1); stageB(1, 1);
  asm volatile("s_waitcnt vmcnt(8)" ::: "memory");
  BAR();

  for (int t2 = 0; t2 < NT; ++t2) {
    const int b = t2 & 1;
    const char* pa = smc + b * 16384;
    const char* pb = smc + 32768 + b * 16384;
    const bool pf = (t2 + 2 < NT);

    bf16x8 af[4][2], bfr[4][2];
#pragma unroll
    for (int mi = 0; mi < 4; ++mi) {
      int row = wm * 64 + mi * 16 + lr;
#pragma unroll
      for (int kk = 0; kk < 2; ++kk)
        af[mi][kk] = *reinterpret_cast<const bf16x8*>(
            pa + row * 128 + ((((kk * 4 + hi) ^ sw)) << 4));
    }
#pragma unroll
    for (int ni = 0; ni < 4; ++ni) {
      int row = wn * 64 + ni * 16 + lr;
#pragma unroll
      for (int kk = 0; kk < 2; ++kk)
        bfr[ni][kk] = *reinterpret_cast<const bf16x8*>(
            pb + row * 128 + ((((kk * 4 + hi) ^ sw)) << 4));
    }
    __builtin_amdgcn_s_setprio(1);
#pragma unroll
    for (int mi = 0; mi < 4; ++mi)
#pragma unroll
      for (int ni = 0; ni < 4; ++ni) {
        acc[mi][ni] = __builtin_amdgcn_mfma_f32_16x16x32_bf16(af[mi][0], bfr[ni][0], acc[mi][ni], 0, 0, 0);
        acc[mi][ni] = __builtin_amdgcn_mfma_f32_16x16x32_bf16(af[mi][1], bfr[ni][1], acc[mi][ni], 0, 0, 0);
      }
    __builtin_amdgcn_s_setprio(0);

    LGKM0();
    BAR();
    if (pf) { stageA(b, t2 + 2); stageB(b, t2 + 2); }
    if (pf) { asm volatile("s_waitcnt vmcnt(8)" ::: "memory"); }
    else    { asm volatile("s_waitcnt vmcnt(0)" ::: "memory"); }
    BAR();
  }

  float bv[4];
#pragma unroll
  for (int ni = 0; ni < 4; ++ni) bv[ni] = bias[n0 + wn * 64 + ni * 16 + lr];
#pragma unroll
  for (int mi = 0; mi < 4; ++mi)
#pragma unroll
    for (int r = 0; r < 4; ++r) {
      long row = m0 + wm * 64 + mi * 16 + hi * 4 + r;
#pragma unroll
      for (int ni = 0; ni < 4; ++ni) {
        long col = n0 + wn * 64 + ni * 16 + lr;
        C[row * N + col] = acc[mi][ni][r] + bv[ni];
      }
    }
}

// ---------------- pass B: scores + bias + softmax + PV ----------------
// Block = 64 s-rows x 10 heads (blockIdx.z selects head half); rs staged once per block.
// grid (NS/64, NB, 2) = 1024 blocks -> 4 blocks/CU.
__global__ __launch_bounds__(256)
void attn_kern(const __hip_bfloat16* __restrict__ qb,
               const __hip_bfloat16* __restrict__ kp,
               const __hip_bfloat16* __restrict__ vt,
               const float* __restrict__ rs,
               const unsigned* __restrict__ gmax,
               const float* __restrict__ sigma,
               __hip_bfloat16* __restrict__ ao_out)
{
  __shared__ __align__(16) float rsl[64][80];
  __shared__ __align__(16) __hip_bfloat16 pl[4][16][NLPV];
  int t = threadIdx.x, lane = t & 63, wi = t >> 6;
  int b = blockIdx.y;
  int s0 = blockIdx.x * 64;
  int h0 = blockIdx.z * (NH / 2);
  int lr = lane & 15, hi = lane >> 4, lk = hi * 8;
  const float c = log1pf(sigma[0] * 0.1f) * dec_f(gmax[0]);

  for (int i = t; i < 64 * NL; i += 256) {
    int rr = i / NL, cc = i - rr * NL;
    rsl[rr][cc] = rs[((long)(b * NS + s0 + rr)) * NL + cc] * c;
  }
#pragma unroll
  for (int r = 0; r < 4; ++r)
    pl[wi][hi * 4 + r][80 + lr] = __float2bfloat16(0.f);
  __syncthreads();

  const int rw = wi * 16;
  const __hip_bfloat16* Qrow = qb + ((long)(b * NS + s0 + rw + lr)) * ND;
  const __hip_bfloat16* Krow = kp + ((long)(b * NLP + lr)) * ND;

  for (int h = h0; h < h0 + NH / 2; ++h) {
    const __hip_bfloat16* Qp = Qrow + h * NDH + lk;
    bf16x8 aq0 = *reinterpret_cast<const bf16x8*>(Qp);
    bf16x8 aq1 = *reinterpret_cast<const bf16x8*>(Qp + 32);

    f32x4 sc[5];
#pragma unroll
    for (int lt = 0; lt < 5; ++lt) {
      const __hip_bfloat16* Kr = Krow + (long)lt * 16 * ND + h * NDH + lk;
      bf16x8 bk0 = *reinterpret_cast<const bf16x8*>(Kr);
      bf16x8 bk1 = *reinterpret_cast<const bf16x8*>(Kr + 32);
      f32x4 z = {0.f, 0.f, 0.f, 0.f};
      z = __builtin_amdgcn_mfma_f32_16x16x32_bf16(aq0, bk0, z, 0, 0, 0);
      sc[lt] = __builtin_amdgcn_mfma_f32_16x16x32_bf16(aq1, bk1, z, 0, 0, 0);
    }

    float sv[5][4];
    float pm[4] = {-1e30f, -1e30f, -1e30f, -1e30f};
#pragma unroll
    for (int lt = 0; lt < 5; ++lt) {
      int l = lt * 16 + lr;
#pragma unroll
      for (int r = 0; r < 4; ++r) {
        if (l < NL) {
          float v = sc[lt][r] * QK_SCALE + rsl[rw + hi * 4 + r][l];
          sv[lt][r] = v;
          pm[r] = fmaxf(pm[r], v);
        } else {
          sv[lt][r] = -1e30f;
        }
      }
    }
#pragma unroll
    for (int r = 0; r < 4; ++r)
#pragma unroll
      for (int k = 8; k >= 1; k >>= 1) pm[r] = fmaxf(pm[r], __shfl_xor(pm[r], k));

    float p[5][4];
    float psum[4] = {0.f, 0.f, 0.f, 0.f};
#pragma unroll
    for (int lt = 0; lt < 5; ++lt) {
      int l = lt * 16 + lr;
#pragma unroll
      for (int r = 0; r < 4; ++r) {
        float e = (l < NL) ? __expf(sv[lt][r] - pm[r]) : 0.f;
        p[lt][r] = e;
        psum[r] += e;
      }
    }
#pragma unroll
    for (int r = 0; r < 4; ++r)
#pragma unroll
      for (int k = 8; k >= 1; k >>= 1) psum[r] += __shfl_xor(psum[r], k);
    float rinv[4];
#pragma unroll
    for (int r = 0; r < 4; ++r) rinv[r] = 1.f / psum[r];

    // fence (1): prior head's PV reads retired (WAR + TBAA-safe)
    LGKM0();

#pragma unroll
    for (int lt = 0; lt < 5; ++lt)
#pragma unroll
      for (int r = 0; r < 4; ++r)
        pl[wi][hi * 4 + r][lt * 16 + lr] = __float2bfloat16(p[lt][r]);

    // fence (2): P-writes complete before PV reads issue (RAW-safe)
    LGKM0();

    f32x4 ao[4];
#pragma unroll
    for (int nt = 0; nt < 4; ++nt) ao[nt] = {0.f, 0.f, 0.f, 0.f};
    const __hip_bfloat16* Vb = vt + ((long)((b * NH + h) * NDH)) * NLPV;
#pragma unroll
    for (int ks = 0; ks < 3; ++ks) {
      bf16x8 pa = *reinterpret_cast<const bf16x8*>(&pl[wi][lr][ks * 32 + lk]);
#pragma unroll
      for (int nt = 0; nt < 4; ++nt) {
        bf16x8 bv = *reinterpret_cast<const bf16x8*>(Vb + ((long)(nt * 16 + lr)) * NLPV + ks * 32 + lk);
        ao[nt] = __builtin_amdgcn_mfma_f32_16x16x32_bf16(pa, bv, ao[nt], 0, 0, 0);
      }
    }

#pragma unroll
    for (int nt = 0; nt < 4; ++nt)
#pragma unroll
      for (int r = 0; r < 4; ++r) {
        int srow = s0 + rw + hi * 4 + r;
        ao_out[((long)(b * NS + srow)) * ND + h * NDH + nt * 16 + lr] =
            __float2bfloat16(ao[nt][r] * rinv[r]);
      }
  }
}

// ---------------- launcher ----------------
extern "C" void kernel_launch(void* const* d_in, const int* in_sizes, int n_in,
                              void* d_out, int out_size, void* d_ws, size_t ws_size,
                              hipStream_t stream)
{
  const float* hs    = (const float*)d_in[0];
  const float* ehs   = (const float*)d_in[1];
  const float* rs    = (const float*)d_in[2];
  const float* Wq    = (const float*)d_in[3];
  const float* Wk    = (const float*)d_in[4];
  const float* Wv    = (const float*)d_in[5];
  const float* Wo    = (const float*)d_in[6];
  const float* bo    = (const float*)d_in[7];
  const float* sigma = (const float*)d_in[8];
  float* out = (float*)d_out;

  char* ws = (char*)d_ws;
  size_t off = 0;
  auto alloc = [&](size_t bytes) {
    void* p = ws + off;
    off = (off + bytes + 255) & ~(size_t)255;
    return p;
  };
  __hip_bfloat16* hsb  = (__hip_bfloat16*)alloc((size_t)NB * NS * ND * 2);   // hs bf16; reused as attn_out
  __hip_bfloat16* qb   = (__hip_bfloat16*)alloc((size_t)NB * NS * ND * 2);
  __hip_bfloat16* wqt  = (__hip_bfloat16*)alloc((size_t)ND * ND * 2);
  __hip_bfloat16* wkvt = (__hip_bfloat16*)alloc((size_t)2560 * NC * 2);      // [Wk^T ; Wv^T]
  __hip_bfloat16* wot  = (__hip_bfloat16*)alloc((size_t)ND * ND * 2);
  __hip_bfloat16* ehsb = (__hip_bfloat16*)alloc((size_t)NB * NL * NC * 2);
  __hip_bfloat16* kp   = (__hip_bfloat16*)alloc((size_t)NB * NLP * ND * 2);
  __hip_bfloat16* vt   = (__hip_bfloat16*)alloc((size_t)NB * NH * NDH * NLPV * 2);
  unsigned* gmax = (unsigned*)alloc(256);

  // 0) init global score-max (encoded; 0 == -inf key). Must run each call.
  hipMemsetAsync(gmax, 0, 4, stream);

  // 1) fused prep: cvt hs, cvt ehs, 4 weight transposes, kp/vt pad zeroing
  prep_kern<<<10896, 256, 0, stream>>>(hs, hsb, ehs, ehsb, Wq, wqt, Wk, Wv, wkvt, Wo, wot, kp, vt);

  // 2) KV = ehs @ [Wk|Wv] with fused repack scatter to kp/vt
  gemm_kv_kern<<<dim3(5, 20), 256, 0, stream>>>(ehsb, wkvt, kp, vt, NB * NL, 2560, NC);

  // 3) Q = hs @ Wq (bf16 out) + fused global score-max (atomic)
  gemm_qmax_kern<<<2560, 256, 0, stream>>>(hsb, wqt, qb, kp, gmax, NB * NS, ND, ND);

  // 4) attention (10 heads per block via z-split -> 4 blocks/CU) -> attn_out (reuses hsb)
  attn_kern<<<dim3(NS / 64, NB, 2), 256, 0, stream>>>(qb, kp, vt, rs, gmax, sigma, hsb);

  // 5) out = attn_out @ Wo + bo  (f32 out)
  gemm_out_kern<<<2560, 256, 0, stream>>>(hsb, wot, out, bo, NB * NS, ND, ND);
}